// Round 1
// 245.648 us; speedup vs baseline: 1.0218x; 1.0218x over previous
//
#include <hip/hip_runtime.h>

#define NODES 65536
#define GNUM  128
#define NPG   512
#define FDIM  128

// workspace layout (bytes) — 49 MB total
#define OFF_A   0u              // 16 MB: A counts u4 [g][dst 512][src 512 nibbles]
#define OFF_WT  (16u<<20)       // 160 KB: Wt bf16 [l][n][k]
#define OFF_HTA (17u<<20)       // 16 MB: hT bf16 [g][feat 128][node 512] (ping)
#define OFF_HTB (33u<<20)       // 16 MB: hT bf16 (pong)

typedef short bf16x8 __attribute__((ext_vector_type(8)));
typedef float f32x4  __attribute__((ext_vector_type(4)));
typedef unsigned short u16;

#define GLB_AS __attribute__((address_space(1)))
#define LDS_AS __attribute__((address_space(3)))

// async global->LDS DMA, 16 B per lane; LDS dest = wave-uniform base + lane*16
static __device__ inline void gload16(const void* g, void* l) {
    __builtin_amdgcn_global_load_lds((const GLB_AS unsigned*)g,
                                     (LDS_AS unsigned*)l, 16, 0, 0);
}

// round-to-nearest-even fp32 -> bf16
static __device__ inline unsigned bf1(float x) {
    unsigned b = __float_as_uint(x);
    return (b + 0x7fffu + ((b >> 16) & 1u)) >> 16;
}
static __device__ inline unsigned pack_bf2(float x, float y) {
    return bf1(x) | (bf1(y) << 16);
}
// 8 u4 counts (one u32) -> bf16x8 (exact: ints <= 15 are exact in bf16)
static __device__ inline bf16x8 cvt8n(unsigned x) {
    union { bf16x8 v; unsigned u[4]; } r;
#pragma unroll
    for (int i = 0; i < 4; ++i) {
        float f0 = (float)((x >> (8 * i)) & 0xFu);
        float f1 = (float)((x >> (8 * i + 4)) & 0xFu);
        r.u[i] = (__float_as_uint(f0) >> 16) | (__float_as_uint(f1) & 0xffff0000u);
    }
    return r.v;
}

// x fp32 [node][feat] -> hT bf16 [g][feat][node]; block = 64 nodes
__global__ __launch_bounds__(256) void k_cvtT(const float* __restrict__ x,
                                              u16* __restrict__ hT) {
    __shared__ char Cs[128 * 144];   // [feat][64 nodes u16], 16B-aligned stride
    int t = threadIdx.x;
    int m0 = blockIdx.x * 64;
    int g = m0 >> 9, ml0 = m0 & 511;
#pragma unroll
    for (int it = 0; it < 8; ++it) {
        int i = t + 256 * it;                 // 2048 float4s
        int nl = i >> 5, fq = i & 31;
        float4 v = *(const float4*)(x + (size_t)(m0 + nl) * FDIM + fq * 4);
        *(u16*)(Cs + (fq * 4 + 0) * 144 + nl * 2) = (u16)bf1(v.x);
        *(u16*)(Cs + (fq * 4 + 1) * 144 + nl * 2) = (u16)bf1(v.y);
        *(u16*)(Cs + (fq * 4 + 2) * 144 + nl * 2) = (u16)bf1(v.z);
        *(u16*)(Cs + (fq * 4 + 3) * 144 + nl * 2) = (u16)bf1(v.w);
    }
    __syncthreads();
    u16* hg = hT + (size_t)g * 65536 + ml0;
#pragma unroll
    for (int j = 0; j < 4; ++j) {
        int idx = t + 256 * j;                // 1024 uint4s
        int f = idx >> 3, piece = idx & 7;
        uint4 v = *(const uint4*)(Cs + f * 144 + piece * 16);
        *(uint4*)((char*)(hg + (size_t)f * 512) + piece * 16) = v;
    }
}

// W[l][k][n] fp32 -> Wt[l][n][k] bf16
__global__ __launch_bounds__(256) void k_wt(const float* __restrict__ W,
                                            u16* __restrict__ wt) {
    int idx = blockIdx.x * 256 + threadIdx.x;   // 5*16384
    int l = idx >> 14, r = idx & 16383;
    int n = r >> 7, k = r & 127;
    wt[idx] = (u16)bf1(W[(l << 14) + k * 128 + n]);
}

// Dense adjacency (u4), SINGLE PASS: one block per graph, 1024 thr, 128 KB
// static LDS (512 dst rows x 64 words). Edge list read once; all atomic lanes
// active. Max cell count ~6 << 15: no nibble overflow.
__global__ __launch_bounds__(1024) void k_adense(const int* __restrict__ src,
                                                 const int* __restrict__ dst,
                                                 unsigned* __restrict__ A4,
                                                 int halfE) {
    __shared__ uint4 cnt4[512 * 16];      // 128 KB
    unsigned* cnt = (unsigned*)cnt4;
    int g = blockIdx.x;
    int t = threadIdx.x;
#pragma unroll
    for (int j = 0; j < 8; ++j) cnt4[t + 1024 * j] = make_uint4(0u, 0u, 0u, 0u);
    __syncthreads();
    int epg = halfE / GNUM;               // 8192
#pragma unroll
    for (int r = 0; r < 2; ++r) {
        int base = r * halfE + g * epg;
        const int4* s4 = (const int4*)(src + base);
        const int4* d4 = (const int4*)(dst + base);
#pragma unroll
        for (int it = 0; it < 2; ++it) {
            int i = t + 1024 * it;
            int4 sv = s4[i], dv = d4[i];
            int s, d;
            s = sv.x & 511; d = dv.x & 511; atomicAdd(&cnt[d * 64 + (s >> 3)], 1u << ((s & 7) * 4));
            s = sv.y & 511; d = dv.y & 511; atomicAdd(&cnt[d * 64 + (s >> 3)], 1u << ((s & 7) * 4));
            s = sv.z & 511; d = dv.z & 511; atomicAdd(&cnt[d * 64 + (s >> 3)], 1u << ((s & 7) * 4));
            s = sv.w & 511; d = dv.w & 511; atomicAdd(&cnt[d * 64 + (s >> 3)], 1u << ((s & 7) * 4));
        }
    }
    __syncthreads();
    uint4* Ao = (uint4*)(A4 + (size_t)g * 512 * 64);
#pragma unroll
    for (int j = 0; j < 8; ++j) Ao[t + 1024 * j] = cnt4[t + 1024 * j];
}

// Fused layer: hT' = relu((A + (1+eps)I) h @ W + b), transposed in/out.
// Round 13: depth-2 DMA pipeline. 3 staging buffers (A 3x4KB + B 3x16KB =
// 60 KB); chunk ch+2 issued each iter; raw s_barrier pairs + counted
// s_waitcnt vmcnt(10/5/0) (5 loads/thread/chunk) so two chunks stay in
// flight ACROSS barriers -- no vmcnt(0) drain in the main loop. P-tile
// (34 KB) aliases the staging buffers (only live after the K-loop, guarded
// by the final barrier). LDS 74->60 KB, still 2 blocks/CU.
__global__ __launch_bounds__(256, 2) void k_layer(const u16* __restrict__ hT,
                                                  u16* __restrict__ hTo,
                                                  const unsigned char* __restrict__ A,
                                                  const u16* __restrict__ wt,
                                                  const float* __restrict__ bias,
                                                  const float* __restrict__ eps) {
    // As[i] = smem + i*4096, i<3          [0, 12288)
    // Bs[i] = smem + 12288 + i*16384      [12288, 61440)
    // Ps    = smem + 12288 (34816 B)      aliases Bs -- used only after K-loop
    __shared__ uint4 smem16[61440 / 16];
    char* smem = (char*)smem16;
    char* Ps = smem + 12288;              // 128 rows x 272 B (bf16 [row][feat])
    int t = threadIdx.x;
    int w = t >> 6, lane = t & 63;
    int q = lane >> 4, ln = lane & 15;
    int g = blockIdx.x & 127, dq = blockIdx.x >> 7;
    const unsigned char* Ab = A + (size_t)g * (512 * 256) + (size_t)dq * 128 * 256;
    const u16* hb = hT + (size_t)g * 65536;

    // A DMA: 256 slots (one per thread); 16 B = half a 32-B row-chunk
    int pA = t;
    const unsigned char* gA = Ab + (pA >> 1) * 256 + (pA & 1) * 16;   // + ch*32
    f32x4 acc[2][8];
#pragma unroll
    for (int mt = 0; mt < 2; ++mt)
#pragma unroll
        for (int nt = 0; nt < 8; ++nt) acc[mt][nt] = (f32x4){0.f, 0.f, 0.f, 0.f};

    // prologue: chunks 0,1 -> buffers 0,1 (B slots XOR-swizzled on global src)
#pragma unroll
    for (int c = 0; c < 2; ++c) {
        gload16(gA + c * 32, smem + c * 4096 + pA * 16);
#pragma unroll
        for (int j = 0; j < 4; ++j) {
            int p = t + 256 * j; int f = p >> 3;
            gload16((const char*)hb + (size_t)f * 1024 + c * 128
                        + (((p & 7) ^ (f & 7)) << 4),
                    smem + 12288 + c * 16384 + p * 16);
        }
    }
    int rA0 = w * 32 + ln;                        // wave rows: rA0, rA0+16
#pragma unroll
    for (int ch = 0; ch < 8; ++ch) {
        char* Asc = smem + (ch % 3) * 4096;
        char* Bsc = smem + 12288 + (ch % 3) * 16384;
        if (ch + 2 < 8) {                          // issue chunk ch+2
            int cn = ch + 2;
            char* Asn = smem + (cn % 3) * 4096;
            char* Bsn = smem + 12288 + (cn % 3) * 16384;
            gload16(gA + cn * 32, Asn + pA * 16);
#pragma unroll
            for (int j = 0; j < 4; ++j) {
                int p = t + 256 * j; int f = p >> 3;
                gload16((const char*)hb + (size_t)f * 1024 + cn * 128
                            + (((p & 7) ^ (f & 7)) << 4),
                        Bsn + p * 16);
            }
        }
        // counted wait: oldest chunk (ch) landed; ch+1, ch+2 stay in flight
        if (ch < 6)      asm volatile("s_waitcnt vmcnt(10)" ::: "memory");
        else if (ch < 7) asm volatile("s_waitcnt vmcnt(5)" ::: "memory");
        else             asm volatile("s_waitcnt vmcnt(0)" ::: "memory");
        __builtin_amdgcn_s_barrier();   // all waves' chunk-ch DMA visible
#pragma unroll
        for (int kcL = 0; kcL < 2; ++kcL) {
            bf16x8 af0 = cvt8n(*(const unsigned*)(Asc + rA0 * 32 + kcL * 16 + q * 4));
            bf16x8 af1 = cvt8n(*(const unsigned*)(Asc + (rA0 + 16) * 32 + kcL * 16 + q * 4));
#pragma unroll
            for (int nt = 0; nt < 8; ++nt) {
                int f = nt * 16 + ln;
                int sB = f * 8 + ((kcL * 4 + q) ^ (f & 7));
                bf16x8 bf = *(const bf16x8*)(Bsc + sB * 16);
                acc[0][nt] = __builtin_amdgcn_mfma_f32_16x16x32_bf16(af0, bf, acc[0][nt], 0, 0, 0);
                acc[1][nt] = __builtin_amdgcn_mfma_f32_16x16x32_bf16(af1, bf, acc[1][nt], 0, 0, 0);
            }
        }
        __builtin_amdgcn_s_barrier();   // reads of buf[ch%3] done (reuse guard)
    }
    // P = pooled + (1+eps)*h_self  -> bf16 P-tile [row][feat], stride 272
    float ep = 1.f + eps[0];
#pragma unroll
    for (int mt = 0; mt < 2; ++mt) {
        int rl0 = w * 32 + mt * 16 + q * 4;       // C rows rl0..rl0+3
        int mb0 = dq * 128 + rl0;
#pragma unroll
        for (int nt = 0; nt < 8; ++nt) {
            int f = nt * 16 + ln;
            uint2 sv = *(const uint2*)(hb + (size_t)f * 512 + mb0);   // self h
            float s0 = __uint_as_float(sv.x << 16);
            float s1 = __uint_as_float(sv.x & 0xffff0000u);
            float s2 = __uint_as_float(sv.y << 16);
            float s3 = __uint_as_float(sv.y & 0xffff0000u);
            f32x4 a = acc[mt][nt];
            *(u16*)(Ps + (rl0 + 0) * 272 + f * 2) = (u16)bf1(fmaf(ep, s0, a[0]));
            *(u16*)(Ps + (rl0 + 1) * 272 + f * 2) = (u16)bf1(fmaf(ep, s1, a[1]));
            *(u16*)(Ps + (rl0 + 2) * 272 + f * 2) = (u16)bf1(fmaf(ep, s2, a[2]));
            *(u16*)(Ps + (rl0 + 3) * 272 + f * 2) = (u16)bf1(fmaf(ep, s3, a[3]));
        }
    }
    __syncthreads();                              // P visible to all waves
    // Phase 2: h'(128x128) = relu(P @ W + b); A-frags from Ps, B from Wt (L1)
    f32x4 acc2[2][8];
#pragma unroll
    for (int mt = 0; mt < 2; ++mt)
#pragma unroll
        for (int nt = 0; nt < 8; ++nt) acc2[mt][nt] = (f32x4){0.f, 0.f, 0.f, 0.f};
#pragma unroll
    for (int ks = 0; ks < 4; ++ks) {
        bf16x8 af0 = *(const bf16x8*)(Ps + rA0 * 272 + ks * 64 + q * 16);
        bf16x8 af1 = *(const bf16x8*)(Ps + (rA0 + 16) * 272 + ks * 64 + q * 16);
#pragma unroll
        for (int nt = 0; nt < 8; ++nt) {
            bf16x8 bf = *(const bf16x8*)(wt + (size_t)(nt * 16 + ln) * 128 + ks * 32 + q * 8);
            acc2[0][nt] = __builtin_amdgcn_mfma_f32_16x16x32_bf16(af0, bf, acc2[0][nt], 0, 0, 0);
            acc2[1][nt] = __builtin_amdgcn_mfma_f32_16x16x32_bf16(af1, bf, acc2[1][nt], 0, 0, 0);
        }
    }
    __syncthreads();                              // all P reads done; reuse as Os
    // epilogue: relu + bias, stage transposed [out-feat][128 nodes], stride 272
#pragma unroll
    for (int mt = 0; mt < 2; ++mt) {
        int rl0 = w * 32 + mt * 16 + q * 4;
#pragma unroll
        for (int nt = 0; nt < 8; ++nt) {
            int n = nt * 16 + ln;
            float bv = bias[n];
            f32x4 a = acc2[mt][nt];
            *(uint2*)(Ps + n * 272 + rl0 * 2) =
                make_uint2(pack_bf2(fmaxf(a[0] + bv, 0.f), fmaxf(a[1] + bv, 0.f)),
                           pack_bf2(fmaxf(a[2] + bv, 0.f), fmaxf(a[3] + bv, 0.f)));
        }
    }
    __syncthreads();
    u16* ho = hTo + (size_t)g * 65536 + dq * 128;
#pragma unroll
    for (int j = 0; j < 8; ++j) {
        int idx = t + 256 * j;                    // 2048 uint4s: 128 f x 256 B
        int f = idx >> 4, piece = idx & 15;
        uint4 v = *(const uint4*)(Ps + f * 272 + piece * 16);
        *(uint4*)((char*)(ho + (size_t)f * 512) + piece * 16) = v;
    }
}

// readout from hT: hg[f] = row-sum; z = relu(hg@fc1+b1); softmax(z@fc2+b2)
__global__ __launch_bounds__(128) void k_r(const u16* __restrict__ hT,
                                           const float* __restrict__ fc1w,
                                           const float* __restrict__ fc1b,
                                           const float* __restrict__ fc2w,
                                           const float* __restrict__ fc2b,
                                           float* __restrict__ out) {
    __shared__ float hg[128], z[128], lg[10];
    int g = blockIdx.x, t = threadIdx.x;
    const uint4* row = (const uint4*)(hT + (size_t)g * 65536 + (size_t)t * 512);
    float acc = 0.f;
#pragma unroll 4
    for (int i = 0; i < 64; ++i) {
        uint4 u = row[i];
        acc += __uint_as_float(u.x << 16) + __uint_as_float(u.x & 0xffff0000u);
        acc += __uint_as_float(u.y << 16) + __uint_as_float(u.y & 0xffff0000u);
        acc += __uint_as_float(u.z << 16) + __uint_as_float(u.z & 0xffff0000u);
        acc += __uint_as_float(u.w << 16) + __uint_as_float(u.w & 0xffff0000u);
    }
    hg[t] = acc;
    __syncthreads();
    float a1 = fc1b[t];
#pragma unroll 4
    for (int k = 0; k < 128; ++k) a1 = fmaf(hg[k], fc1w[k * 128 + t], a1);
    z[t] = fmaxf(a1, 0.f);
    __syncthreads();
    if (t < 10) {
        float l2 = fc2b[t];
        for (int k = 0; k < 128; ++k) l2 = fmaf(z[k], fc2w[k * 10 + t], l2);
        lg[t] = l2;
    }
    __syncthreads();
    if (t < 10) {
        float m = lg[0];
        for (int c = 1; c < 10; ++c) m = fmaxf(m, lg[c]);
        float ssum = 0.f;
        for (int c = 0; c < 10; ++c) ssum += expf(lg[c] - m);
        out[g * 10 + t] = expf(lg[t] - m) / ssum;
    }
}

extern "C" void kernel_launch(void* const* d_in, const int* in_sizes, int n_in,
                              void* d_out, int out_size, void* d_ws, size_t ws_size,
                              hipStream_t stream) {
    const float* x    = (const float*)d_in[0];
    const float* eps  = (const float*)d_in[1];
    const float* W    = (const float*)d_in[2];
    const float* b    = (const float*)d_in[3];
    const float* fc1w = (const float*)d_in[4];
    const float* fc1b = (const float*)d_in[5];
    const float* fc2w = (const float*)d_in[6];
    const float* fc2b = (const float*)d_in[7];
    const int*   src  = (const int*)d_in[8];
    const int*   dst  = (const int*)d_in[9];
    int E = in_sizes[8];
    int halfE = E >> 1;

    char* ws  = (char*)d_ws;
    unsigned char* Abuf = (unsigned char*)(ws + OFF_A);
    u16*  wtb = (u16*)(ws + OFF_WT);
    u16*  hta = (u16*)(ws + OFF_HTA);
    u16*  htb = (u16*)(ws + OFF_HTB);
    float* out = (float*)d_out;

    k_cvtT<<<NODES / 64, 256, 0, stream>>>(x, hta);
    k_wt<<<5 * 128 * 128 / 256, 256, 0, stream>>>(W, wtb);
    k_adense<<<GNUM, 1024, 0, stream>>>(src, dst, (unsigned*)Abuf, halfE);

    u16* cur = hta;
    u16* nxt = htb;
    for (int l = 0; l < 5; ++l) {
        k_layer<<<GNUM * 4, 256, 0, stream>>>(cur, nxt, Abuf,
                                              wtb + l * 128 * 128, b + l * 128, eps + l);
        u16* tmp = cur; cur = nxt; nxt = tmp;
    }
    k_r<<<GNUM, 128, 0, stream>>>(cur, fc1w, fc1b, fc2w, fc2b, out);
}